// Round 10
// baseline (13.531 us; speedup 1.0000x reference)
//
#include <hip/hip_runtime.h>

// WImage via moment expansion — ONE dispatch, ZERO LDS, ZERO barriers.
//
// aff(n,c) = exp(-2(n-c)^2) = e^{-2c^2} * sum_k (c^k/k!) * mu_k(n),
//   mu_k(n) = (4n)^k e^{-2n^2};  muh_k = mu_k - delta_k0  (zero-padding -> 0)
// tot(c) = e^{-2c^2} * ( sum_k (c^k/k!) * S_k + 441 ),  S_k = 21x21 box sum of muh_k
// out = (c + 0.05*(tot-1) - mn) * scale - 1.   NMOM=13 (absmax floor, r5-r8).
//
// r10 = occupancy experiment: R=2 rows/wave -> 3072 waves = 3.0/SIMD balanced
// (vs r9's 2.0/SIMD). Issue work +30%, latency hiding +50%. Discriminates
// fixed-floor vs latency-bound (see round notes).

#define NMOM 13
#define HH   256
#define WW   256
#define RW   2               // output rows per wave
#define HRW  (RW + 20)       // 22 halo rows per wave
#define BROWS (2 * RW)       // 4 rows per block (2 waves)

#define K2L  (-2.8853900817779268f)   // -2*log2(e)

template <int CTRL, int RMASK>
__device__ __forceinline__ float dpp_add(float v) {
    int s = __builtin_amdgcn_update_dpp(0, __builtin_bit_cast(int, v),
                                        CTRL, RMASK, 0xf, true);
    return v + __builtin_bit_cast(float, s);
}

// canonical wave64 inclusive add-scan (validated r4-r9)
__device__ __forceinline__ float wave_iscan(float v) {
    v = dpp_add<0x111, 0xf>(v);   // row_shr:1
    v = dpp_add<0x112, 0xf>(v);   // row_shr:2
    v = dpp_add<0x114, 0xf>(v);   // row_shr:4
    v = dpp_add<0x118, 0xf>(v);   // row_shr:8
    v = dpp_add<0x142, 0xa>(v);   // row_bcast:15 -> rows 1,3
    v = dpp_add<0x143, 0xc>(v);   // row_bcast:31 -> rows 2,3
    return v;
}

__global__ __launch_bounds__(128)
void wimage_reg(const float* __restrict__ img, float* __restrict__ out) {
    const int t    = threadIdx.x;
    const int lane = t & 63;
    const int w    = t >> 6;                    // wave 0..1

    const int x0 = blockIdx.x * 32;             // output col base
    const int yb = blockIdx.y * BROWS + RW * w; // this wave's first output row
    const int ch = blockIdx.z;
    const float* __restrict__ plane = img + ch * (HH * WW);

    const int  gx  = x0 - 10 + lane;            // this lane's halo column
    const bool xok = (unsigned)gx < (unsigned)WW;

    // hoisted bpermute byte-addresses for the two window taps
    const int bp_hi = ((lane + 20) & 63) << 2;  // P[xo+20]
    const int bp_lo = ((lane - 1) & 63) << 2;   // P[xo-1] (lane0 masked)

    // ---- column state: mu_0 and 4n for 22 halo rows (out-of-image -> n=0)
    float mu[HRW], n4[HRW];
    #pragma unroll
    for (int m = 0; m < HRW; ++m) {
        const int gy = yb - 10 + m;
        float n = 0.0f;
        if (xok && (unsigned)gy < (unsigned)HH) n = plane[gy * WW + gx];
        n4[m] = 4.0f * n;
        mu[m] = __builtin_amdgcn_exp2f(K2L * n * n);   // n=0 -> 1
    }

    // center values for the RW output rows (lanes 0..31 = output cols)
    float c[RW], pw[RW], acc[RW];
    #pragma unroll
    for (int j = 0; j < RW; ++j) {
        c[j]  = (lane < 32) ? plane[(yb + j) * WW + x0 + lane] : 0.0f;
        pw[j] = 1.0f;
        acc[j] = 0.0f;
    }

    const float IKP1[NMOM] = {        // 1/(k+1)
        1.0f, 0.5f, 1.0f/3.0f, 0.25f, 0.2f, 1.0f/6.0f, 1.0f/7.0f, 0.125f,
        1.0f/9.0f, 0.1f, 1.0f/11.0f, 1.0f/12.0f, 1.0f/13.0f };

    #pragma unroll
    for (int k = 0; k < NMOM; ++k) {
        if (k > 0) {
            #pragma unroll
            for (int m = 0; m < HRW; ++m) mu[m] *= n4[m];   // mu_{k-1} -> mu_k
        }

        // vertical 21-window per column, in registers (sum + 1 slide)
        float sv0 = mu[0];
        #pragma unroll
        for (int m = 1; m < 21; ++m) sv0 += mu[m];
        float sv1 = sv0 - mu[0] + mu[21];
        if (k == 0) { sv0 -= 21.0f; sv1 -= 21.0f; }

        float sv[RW] = { sv0, sv1 };
        #pragma unroll
        for (int j = 0; j < RW; ++j) {
            float p  = wave_iscan(sv[j]);
            const int pi = __builtin_bit_cast(int, p);
            float ph = __builtin_bit_cast(float, __builtin_amdgcn_ds_bpermute(bp_hi, pi));
            float pl = __builtin_bit_cast(float, __builtin_amdgcn_ds_bpermute(bp_lo, pi));
            float S  = ph - ((lane > 0) ? pl : 0.0f);
            acc[j] = fmaf(S, pw[j], acc[j]);
            pw[j] *= c[j] * IKP1[k];            // c^k/k! -> c^{k+1}/(k+1)!
        }
    }

    // ---- epilogue: tot = e^{-2c^2}(acc+441); out = (c+0.05(tot-1)-mn)*scale-1
    if (lane < 32) {
        const float alpha = 0.05f;
        const float mn    = -0.99261982218614470f;   // -1 + 22*exp(-8)
        const float scale = 2.0f / (23.0f - mn);
        #pragma unroll
        for (int j = 0; j < RW; ++j) {
            const float cc  = c[j];
            const float e2c = __builtin_amdgcn_exp2f(K2L * cc * cc);
            const float tot = e2c * (acc[j] + 441.0f);
            out[ch * (HH * WW) + (yb + j) * WW + x0 + lane] =
                (cc + alpha * (tot - 1.0f) - mn) * scale - 1.0f;
        }
    }
}

extern "C" void kernel_launch(void* const* d_in, const int* in_sizes, int n_in,
                              void* d_out, int out_size, void* d_ws, size_t ws_size,
                              hipStream_t stream) {
    (void)in_sizes; (void)n_in; (void)out_size; (void)d_ws; (void)ws_size;
    const float* img = (const float*)d_in[0];  // d_in[1] = kernel size (21), hardcoded
    float* out = (float*)d_out;

    // 8 x 64 x 3 = 1536 blocks (128 thr = 2 waves) -> 3072 waves = 3.0/SIMD
    dim3 grid(WW / 32, HH / BROWS, 3);
    wimage_reg<<<grid, dim3(128), 0, stream>>>(img, out);
}

// Round 11
// 12.798 us; speedup vs baseline: 1.0573x; 1.0573x over previous
//
#include <hip/hip_runtime.h>

// WImage via moment expansion — ONE dispatch, ZERO LDS, ZERO barriers.
//
// aff(n,c) = exp(-2(n-c)^2) = e^{-2c^2} * sum_k (c^k/k!) * mu_k(n),
//   mu_k(n) = (4n)^k e^{-2n^2};  muh_k = mu_k - delta_k0  (zero-padding -> 0)
// tot(c) = e^{-2c^2} * ( sum_k (c^k/k!) * S_k + 441 ),  S_k = 21x21 box sum of muh_k
// out = (c + 0.05*(tot-1) - mn) * scale - 1.   NMOM=13 (absmax floor).
//
// Best measured config (r8): wave = 64 halo columns, R=4 output rows/wave,
// 256-thread blocks, 384 blocks. r9/r10 established the session is at a fixed
// dispatch floor (~11 us): issue work +-40% moved dur only +-3%. This is r8
// + hoisted bpermute addresses (r9's micro-win). Expected ~12.7-13.0 us.

#define NMOM 13
#define HH   256
#define WW   256
#define HRW  24              // halo rows per wave (4 out rows + 20)

#define K2L  (-2.8853900817779268f)   // -2*log2(e)

template <int CTRL, int RMASK>
__device__ __forceinline__ float dpp_add(float v) {
    int s = __builtin_amdgcn_update_dpp(0, __builtin_bit_cast(int, v),
                                        CTRL, RMASK, 0xf, true);
    return v + __builtin_bit_cast(float, s);
}

// canonical wave64 inclusive add-scan (validated r4-r10)
__device__ __forceinline__ float wave_iscan(float v) {
    v = dpp_add<0x111, 0xf>(v);   // row_shr:1
    v = dpp_add<0x112, 0xf>(v);   // row_shr:2
    v = dpp_add<0x114, 0xf>(v);   // row_shr:4
    v = dpp_add<0x118, 0xf>(v);   // row_shr:8
    v = dpp_add<0x142, 0xa>(v);   // row_bcast:15 -> rows 1,3
    v = dpp_add<0x143, 0xc>(v);   // row_bcast:31 -> rows 2,3
    return v;
}

__global__ __launch_bounds__(256)
void wimage_reg(const float* __restrict__ img, float* __restrict__ out) {
    const int t    = threadIdx.x;
    const int lane = t & 63;
    const int w    = t >> 6;                 // wave 0..3

    const int x0 = blockIdx.x * 32;          // output col base
    const int yb = blockIdx.y * 16 + 4 * w;  // this wave's first output row
    const int ch = blockIdx.z;
    const float* __restrict__ plane = img + ch * (HH * WW);

    const int  gx  = x0 - 10 + lane;         // this lane's halo column
    const bool xok = (unsigned)gx < (unsigned)WW;

    // hoisted bpermute byte-addresses for the two window taps
    const int bp_hi = ((lane + 20) & 63) << 2;  // P[xo+20]
    const int bp_lo = ((lane - 1) & 63) << 2;   // P[xo-1] (lane0 masked)

    // ---- column state: mu_0 and 4n for 24 halo rows (out-of-image -> n=0)
    float mu[HRW], n4[HRW];
    #pragma unroll
    for (int m = 0; m < HRW; ++m) {
        const int gy = yb - 10 + m;
        float n = 0.0f;
        if (xok && (unsigned)gy < (unsigned)HH) n = plane[gy * WW + gx];
        n4[m] = 4.0f * n;
        mu[m] = __builtin_amdgcn_exp2f(K2L * n * n);   // n=0 -> 1
    }

    // center values for the 4 output rows (lanes 0..31 = output cols)
    float c[4], pw[4], acc[4];
    #pragma unroll
    for (int j = 0; j < 4; ++j) {
        c[j]  = (lane < 32) ? plane[(yb + j) * WW + x0 + lane] : 0.0f;
        pw[j] = 1.0f;
        acc[j] = 0.0f;
    }

    const float IKP1[NMOM] = {        // 1/(k+1)
        1.0f, 0.5f, 1.0f/3.0f, 0.25f, 0.2f, 1.0f/6.0f, 1.0f/7.0f, 0.125f,
        1.0f/9.0f, 0.1f, 1.0f/11.0f, 1.0f/12.0f, 1.0f/13.0f };

    #pragma unroll
    for (int k = 0; k < NMOM; ++k) {
        if (k > 0) {
            #pragma unroll
            for (int m = 0; m < HRW; ++m) mu[m] *= n4[m];   // mu_{k-1} -> mu_k
        }

        // vertical 21-window per column, in registers (sum + 3 slides)
        float sv0 = mu[0];
        #pragma unroll
        for (int m = 1; m < 21; ++m) sv0 += mu[m];
        float sv1 = sv0 - mu[0] + mu[21];
        float sv2 = sv1 - mu[1] + mu[22];
        float sv3 = sv2 - mu[2] + mu[23];
        if (k == 0) { sv0 -= 21.0f; sv1 -= 21.0f; sv2 -= 21.0f; sv3 -= 21.0f; }

        float sv[4] = { sv0, sv1, sv2, sv3 };
        #pragma unroll
        for (int j = 0; j < 4; ++j) {
            float p  = wave_iscan(sv[j]);
            const int pi = __builtin_bit_cast(int, p);
            float ph = __builtin_bit_cast(float, __builtin_amdgcn_ds_bpermute(bp_hi, pi));
            float pl = __builtin_bit_cast(float, __builtin_amdgcn_ds_bpermute(bp_lo, pi));
            float S  = ph - ((lane > 0) ? pl : 0.0f);
            acc[j] = fmaf(S, pw[j], acc[j]);
            pw[j] *= c[j] * IKP1[k];            // c^k/k! -> c^{k+1}/(k+1)!
        }
    }

    // ---- epilogue: tot = e^{-2c^2}(acc+441); out = (c+0.05(tot-1)-mn)*scale-1
    if (lane < 32) {
        const float alpha = 0.05f;
        const float mn    = -0.99261982218614470f;   // -1 + 22*exp(-8)
        const float scale = 2.0f / (23.0f - mn);
        #pragma unroll
        for (int j = 0; j < 4; ++j) {
            const float cc  = c[j];
            const float e2c = __builtin_amdgcn_exp2f(K2L * cc * cc);
            const float tot = e2c * (acc[j] + 441.0f);
            out[ch * (HH * WW) + (yb + j) * WW + x0 + lane] =
                (cc + alpha * (tot - 1.0f) - mn) * scale - 1.0f;
        }
    }
}

extern "C" void kernel_launch(void* const* d_in, const int* in_sizes, int n_in,
                              void* d_out, int out_size, void* d_ws, size_t ws_size,
                              hipStream_t stream) {
    (void)in_sizes; (void)n_in; (void)out_size; (void)d_ws; (void)ws_size;
    const float* img = (const float*)d_in[0];  // d_in[1] = kernel size (21), hardcoded
    float* out = (float*)d_out;

    dim3 grid(WW / 32, HH / 16, 3);            // 8 x 16 x 3 = 384 blocks
    wimage_reg<<<grid, dim3(256), 0, stream>>>(img, out);
}